// Round 1
// baseline (2236.706 us; speedup 1.0000x reference)
//
#include <hip/hip_runtime.h>
#include <hip/hip_bf16.h>
#include <stdint.h>

// SparseMLP grouped GEMM: out = (gelu_tanh(x @ w1)) @ w2, per-expert blocks.
// T=8192 tokens, H=2048, FF=8192, E=8 experts, T/E=1024 rows per expert.
// Strategy: bf16 MFMA (16x16x32), fp32->bf16 conversion fused into LDS staging.

#define T_TOK 8192
#define H_DIM 2048
#define FF_DIM 8192
#define NEXP 8
#define TE (T_TOK / NEXP)   // 1024

#define BM 128
#define BN 128
#define BK 64
#define LDK 72              // padded LDS leading dim (elems): 144B rows, 16B aligned
#define NTHR 256

typedef __attribute__((ext_vector_type(8))) short bf16x8;   // 8 bf16 = 4 VGPR (MFMA operand)
typedef __attribute__((ext_vector_type(4))) float f32x4;    // MFMA accumulator
typedef __attribute__((ext_vector_type(4))) __bf16 bf16x4;  // 8B packed store

__device__ __forceinline__ float gelu_tanh_f(float x) {
    // 0.5x(1+tanh(c(x+0.044715x^3))) == x * sigmoid(2c(x+0.044715x^3))
    float u = x * (0.7978845608028654f + 0.0356774081f * (x * x));
    return x / (1.0f + __expf(-2.0f * u));
}

// ---------------------------------------------------------------------------
// GEMM1: h[e,1024,8192] = gelu(x[e,1024,2048] @ w1[e,2048,8192]), h in bf16
// ---------------------------------------------------------------------------
__global__ __launch_bounds__(NTHR, 2)
void moe_gemm1_gelu(const float* __restrict__ X, const float* __restrict__ W1,
                    __bf16* __restrict__ Hout) {
    const int nb = blockIdx.x, mb = blockIdx.y, e = blockIdx.z;
    const int tid  = threadIdx.x;
    const int lane = tid & 63;
    const int wave = tid >> 6;
    const int wr = wave >> 1, wc = wave & 1;

    __shared__ __bf16 sA[BM * LDK];   // [m][k]
    __shared__ __bf16 sB[BN * LDK];   // [n][k] (transposed during staging)

    const float* Ag = X  + (size_t)(e * TE + mb * BM) * H_DIM;
    const float* Bg = W1 + (size_t)e * H_DIM * FF_DIM + (size_t)nb * BN;

    // A staging map: iter i in [0,8): row = i*16 + (tid>>4), kcol = (tid&15)*4
    const int a_row = tid >> 4;
    const int a_col = (tid & 15) * 4;
    // B staging map: column n = tid&127, k-halves: k0h = (tid>>7)*32 + j, j in [0,32)
    const int b_n  = tid & 127;
    const int b_k0 = (tid >> 7) * 32;

    float4 av[8];
    float  bv[32];

    auto loadAB = [&](int k0) {
        #pragma unroll
        for (int j = 0; j < 32; j++)
            bv[j] = Bg[(size_t)(k0 + b_k0 + j) * FF_DIM + b_n];
        #pragma unroll
        for (int i = 0; i < 8; i++)
            av[i] = *(const float4*)(Ag + (size_t)(i * 16 + a_row) * H_DIM + k0 + a_col);
    };
    auto stageAB = [&]() {
        #pragma unroll
        for (int i = 0; i < 8; i++) {
            bf16x4 w = { (__bf16)av[i].x, (__bf16)av[i].y, (__bf16)av[i].z, (__bf16)av[i].w };
            *(bf16x4*)&sA[(i * 16 + a_row) * LDK + a_col] = w;
        }
        #pragma unroll
        for (int j4 = 0; j4 < 8; j4++) {
            bf16x4 w = { (__bf16)bv[j4*4+0], (__bf16)bv[j4*4+1],
                         (__bf16)bv[j4*4+2], (__bf16)bv[j4*4+3] };
            *(bf16x4*)&sB[b_n * LDK + b_k0 + j4 * 4] = w;
        }
    };

    f32x4 acc[4][4] = {};
    const int fr  = lane & 15;
    const int fko = (lane >> 4) * 8;

    loadAB(0);
    for (int ks = 0; ks < H_DIM / BK; ks++) {
        __syncthreads();
        stageAB();
        __syncthreads();
        if (ks + 1 < H_DIM / BK) loadAB((ks + 1) * BK);   // prefetch overlaps MFMA below
        #pragma unroll
        for (int ksl = 0; ksl < 2; ksl++) {
            bf16x8 af[4], bfr[4];
            #pragma unroll
            for (int mf = 0; mf < 4; mf++)
                af[mf] = *(const bf16x8*)&sA[(wr * 64 + mf * 16 + fr) * LDK + ksl * 32 + fko];
            #pragma unroll
            for (int nf = 0; nf < 4; nf++)
                bfr[nf] = *(const bf16x8*)&sB[(wc * 64 + nf * 16 + fr) * LDK + ksl * 32 + fko];
            #pragma unroll
            for (int mf = 0; mf < 4; mf++)
                #pragma unroll
                for (int nf = 0; nf < 4; nf++)
                    acc[mf][nf] = __builtin_amdgcn_mfma_f32_16x16x32_bf16(
                        af[mf], bfr[nf], acc[mf][nf], 0, 0, 0);
        }
    }

    // Epilogue: gelu in fp32, cast bf16, store. C/D layout: col=lane&15, row=(lane>>4)*4+r
    __bf16* Hg = Hout + (size_t)(e * TE + mb * BM + wr * 64) * FF_DIM + nb * BN + wc * 64;
    const int r0 = (lane >> 4) * 4;
    #pragma unroll
    for (int mf = 0; mf < 4; mf++)
        #pragma unroll
        for (int nf = 0; nf < 4; nf++)
            #pragma unroll
            for (int r = 0; r < 4; r++)
                Hg[(size_t)(mf * 16 + r0 + r) * FF_DIM + nf * 16 + fr] =
                    (__bf16)gelu_tanh_f(acc[mf][nf][r]);
}

// ---------------------------------------------------------------------------
// GEMM2: out[e,1024,2048] = h[e,1024,8192](bf16) @ w2[e,8192,2048], fp32 out
// ---------------------------------------------------------------------------
__global__ __launch_bounds__(NTHR, 2)
void moe_gemm2(const __bf16* __restrict__ Hin, const float* __restrict__ W2,
               float* __restrict__ Out) {
    const int nb = blockIdx.x, mb = blockIdx.y, e = blockIdx.z;
    const int tid  = threadIdx.x;
    const int lane = tid & 63;
    const int wave = tid >> 6;
    const int wr = wave >> 1, wc = wave & 1;

    __shared__ __bf16 sA[BM * LDK];
    __shared__ __bf16 sB[BN * LDK];

    const __bf16* Ag = Hin + (size_t)(e * TE + mb * BM) * FF_DIM;
    const float*  Bg = W2  + (size_t)e * FF_DIM * H_DIM + (size_t)nb * BN;

    // A staging (bf16 src, 16B loads): iter i in [0,4): row = i*32 + (tid>>3), kcol=(tid&7)*8
    const int a_row = tid >> 3;
    const int a_col = (tid & 7) * 8;
    const int b_n  = tid & 127;
    const int b_k0 = (tid >> 7) * 32;

    uint4 av[4];
    float bv[32];

    auto loadAB = [&](int k0) {
        #pragma unroll
        for (int j = 0; j < 32; j++)
            bv[j] = Bg[(size_t)(k0 + b_k0 + j) * H_DIM + b_n];
        #pragma unroll
        for (int i = 0; i < 4; i++)
            av[i] = *(const uint4*)(Ag + (size_t)(i * 32 + a_row) * FF_DIM + k0 + a_col);
    };
    auto stageAB = [&]() {
        #pragma unroll
        for (int i = 0; i < 4; i++)
            *(uint4*)&sA[(i * 32 + a_row) * LDK + a_col] = av[i];
        #pragma unroll
        for (int j4 = 0; j4 < 8; j4++) {
            bf16x4 w = { (__bf16)bv[j4*4+0], (__bf16)bv[j4*4+1],
                         (__bf16)bv[j4*4+2], (__bf16)bv[j4*4+3] };
            *(bf16x4*)&sB[b_n * LDK + b_k0 + j4 * 4] = w;
        }
    };

    f32x4 acc[4][4] = {};
    const int fr  = lane & 15;
    const int fko = (lane >> 4) * 8;

    loadAB(0);
    for (int ks = 0; ks < FF_DIM / BK; ks++) {
        __syncthreads();
        stageAB();
        __syncthreads();
        if (ks + 1 < FF_DIM / BK) loadAB((ks + 1) * BK);
        #pragma unroll
        for (int ksl = 0; ksl < 2; ksl++) {
            bf16x8 af[4], bfr[4];
            #pragma unroll
            for (int mf = 0; mf < 4; mf++)
                af[mf] = *(const bf16x8*)&sA[(wr * 64 + mf * 16 + fr) * LDK + ksl * 32 + fko];
            #pragma unroll
            for (int nf = 0; nf < 4; nf++)
                bfr[nf] = *(const bf16x8*)&sB[(wc * 64 + nf * 16 + fr) * LDK + ksl * 32 + fko];
            #pragma unroll
            for (int mf = 0; mf < 4; mf++)
                #pragma unroll
                for (int nf = 0; nf < 4; nf++)
                    acc[mf][nf] = __builtin_amdgcn_mfma_f32_16x16x32_bf16(
                        af[mf], bfr[nf], acc[mf][nf], 0, 0, 0);
        }
    }

    float* Og = Out + (size_t)(e * TE + mb * BM + wr * 64) * H_DIM + nb * BN + wc * 64;
    const int r0 = (lane >> 4) * 4;
    #pragma unroll
    for (int mf = 0; mf < 4; mf++)
        #pragma unroll
        for (int nf = 0; nf < 4; nf++)
            #pragma unroll
            for (int r = 0; r < 4; r++)
                Og[(size_t)(mf * 16 + r0 + r) * H_DIM + nf * 16 + fr] = acc[mf][nf][r];
}

extern "C" void kernel_launch(void* const* d_in, const int* in_sizes, int n_in,
                              void* d_out, int out_size, void* d_ws, size_t ws_size,
                              hipStream_t stream) {
    const float* x  = (const float*)d_in[0];
    const float* w1 = (const float*)d_in[1];
    const float* w2 = (const float*)d_in[2];
    // d_in[3] = num_experts (scalar) — fixed at compile time (E=8)
    float* out = (float*)d_out;
    __bf16* h = (__bf16*)d_ws;   // needs 8192*8192*2 = 128 MB scratch

    dim3 g1(FF_DIM / BN, TE / BM, NEXP);   // (64, 8, 8) = 4096 blocks
    dim3 g2(H_DIM / BN,  TE / BM, NEXP);   // (16, 8, 8) = 1024 blocks
    moe_gemm1_gelu<<<g1, NTHR, 0, stream>>>(x, w1, h);
    moe_gemm2<<<g2, NTHR, 0, stream>>>(h, w2, out);
}